// Round 2
// baseline (447.387 us; speedup 1.0000x reference)
//
#include <hip/hip_runtime.h>
#include <math.h>

#define NN 4096
#define BB 8
#define NV4 (NN / 4)        // float4 per row = 1024
#define KSPLIT 4            // waves per row-pair, each owns K/4
#define KQ (NV4 / KSPLIT)   // 256 float4 per k-slice
#define KITERS (KQ / 64)    // 4 chunk iterations per wave

__global__ __launch_bounds__(256, 4) void attgru_fused_kernel(
    const float* __restrict__ x,   const float* __restrict__ h,
    const float* __restrict__ adj, const float* __restrict__ Whr,
    const float* __restrict__ bhr, const float* __restrict__ Whz,
    const float* __restrict__ bhz, const float* __restrict__ Whn,
    const float* __restrict__ bhn, float* __restrict__ out)
{
    const int lane = threadIdx.x & 63;
    const int wave = threadIdx.x >> 6;       // 0..3 = k-slice
    const int row0 = blockIdx.x * 2;         // 2 rows per block

    const float4* x4 = reinterpret_cast<const float4*>(x);
    const float4* h4 = reinterpret_cast<const float4*>(h);
    const size_t rbase = (size_t)row0 * NV4;
    const float4* A0 = reinterpret_cast<const float4*>(adj) + rbase;
    const float4* A1 = A0 + NV4;
    const float4* R0 = reinterpret_cast<const float4*>(Whr) + rbase;
    const float4* R1 = R0 + NV4;
    const float4* Z0 = reinterpret_cast<const float4*>(Whz) + rbase;
    const float4* Z1 = Z0 + NV4;
    const float4* G0 = reinterpret_cast<const float4*>(Whn) + rbase;
    const float4* G1 = G0 + NV4;

    float accA[2][BB], accR[2][BB], accZ[2][BB], accN[2][BB];
#pragma unroll
    for (int r = 0; r < 2; ++r)
#pragma unroll
        for (int b = 0; b < BB; ++b) {
            accA[r][b] = 0.f; accR[r][b] = 0.f; accZ[r][b] = 0.f; accN[r][b] = 0.f;
        }

    const int kbase = wave * KQ;
#pragma unroll
    for (int it = 0; it < KITERS; ++it) {
        const int idx = kbase + it * 64 + lane;
        const float4 a0 = A0[idx], a1 = A1[idx];
        const float4 r0 = R0[idx], r1 = R1[idx];
        const float4 z0 = Z0[idx], z1 = Z1[idx];
        const float4 g0 = G0[idx], g1 = G1[idx];
#pragma unroll
        for (int b = 0; b < BB; ++b) {
            const float4 xb = x4[b * NV4 + idx];
            const float4 hb = h4[b * NV4 + idx];
            accA[0][b] += a0.x * xb.x + a0.y * xb.y + a0.z * xb.z + a0.w * xb.w;
            accA[1][b] += a1.x * xb.x + a1.y * xb.y + a1.z * xb.z + a1.w * xb.w;
            accR[0][b] += r0.x * hb.x + r0.y * hb.y + r0.z * hb.z + r0.w * hb.w;
            accR[1][b] += r1.x * hb.x + r1.y * hb.y + r1.z * hb.z + r1.w * hb.w;
            accZ[0][b] += z0.x * hb.x + z0.y * hb.y + z0.z * hb.z + z0.w * hb.w;
            accZ[1][b] += z1.x * hb.x + z1.y * hb.y + z1.z * hb.z + z1.w * hb.w;
            accN[0][b] += g0.x * hb.x + g0.y * hb.y + g0.z * hb.z + g0.w * hb.w;
            accN[1][b] += g1.x * hb.x + g1.y * hb.y + g1.z * hb.z + g1.w * hb.w;
        }
    }

    // 4-step butterfly: sums within each contiguous 16-lane group.
#pragma unroll
    for (int off = 1; off <= 8; off <<= 1) {
#pragma unroll
        for (int r = 0; r < 2; ++r)
#pragma unroll
            for (int b = 0; b < BB; ++b) {
                accA[r][b] += __shfl_xor(accA[r][b], off);
                accR[r][b] += __shfl_xor(accR[r][b], off);
                accZ[r][b] += __shfl_xor(accZ[r][b], off);
                accN[r][b] += __shfl_xor(accN[r][b], off);
            }
    }

    // Cross-group + cross-wave reduction through LDS: 16 partial sets.
    __shared__ float4 red[KSPLIT * 4][2][BB];   // 4 KB
    if ((lane & 15) == 0) {
        const int slot = wave * 4 + (lane >> 4);
#pragma unroll
        for (int r = 0; r < 2; ++r)
#pragma unroll
            for (int b = 0; b < BB; ++b)
                red[slot][r][b] =
                    make_float4(accA[r][b], accR[r][b], accZ[r][b], accN[r][b]);
    }
    __syncthreads();

    const int t = threadIdx.x;
    if (t < 16) {
        const int r = t >> 3, b = t & 7;
        float4 s = red[0][r][b];
#pragma unroll
        for (int k = 1; k < KSPLIT * 4; ++k) {
            const float4 p = red[k][r][b];
            s.x += p.x; s.y += p.y; s.z += p.z; s.w += p.w;
        }
        const int row = row0 + r;
        const float agg = s.x;
        const float rg = 1.f / (1.f + __expf(-(agg + s.y + bhr[row])));
        const float zg = 1.f / (1.f + __expf(-(agg + s.z + bhz[row])));
        const float ng = tanhf(agg + rg * (s.w + bhn[row]));
        const float hv = h[b * NN + row];
        out[b * NN + row] = (1.f - zg) * ng + zg * hv;
    }
}

extern "C" void kernel_launch(void* const* d_in, const int* in_sizes, int n_in,
                              void* d_out, int out_size, void* d_ws, size_t ws_size,
                              hipStream_t stream) {
    const float* x   = (const float*)d_in[0];
    const float* h   = (const float*)d_in[1];
    const float* adj = (const float*)d_in[2];
    const float* Whr = (const float*)d_in[3];
    const float* bhr = (const float*)d_in[4];
    const float* Whz = (const float*)d_in[5];
    const float* bhz = (const float*)d_in[6];
    const float* Whn = (const float*)d_in[7];
    const float* bhn = (const float*)d_in[8];
    float* out = (float*)d_out;

    const int grid = NN / 2;   // 2048 blocks, 4 waves each
    attgru_fused_kernel<<<grid, 256, 0, stream>>>(x, h, adj, Whr, bhr, Whz, bhz,
                                                  Whn, bhn, out);
}

// Round 3
// 233.978 us; speedup vs baseline: 1.9121x; 1.9121x over previous
//
#include <hip/hip_runtime.h>
#include <math.h>

#define NN 4096
#define BB 8
#define NV4 (NN / 4)   // float4 per row = 1024

// Block = 4 waves; wave g computes gate g (adj·x, h·Whr, h·Whz, h·Whn)
// for the block's 2 rows. 16 accumulators/thread, no K-loop unroll ->
// no spills (R1 post-mortem: unrolled loads + 128 accs = 912 MB scratch).
__global__ __launch_bounds__(256, 4) void attgru_fused_kernel(
    const float* __restrict__ x,   const float* __restrict__ h,
    const float* __restrict__ adj, const float* __restrict__ Whr,
    const float* __restrict__ bhr, const float* __restrict__ Whz,
    const float* __restrict__ bhz, const float* __restrict__ Whn,
    const float* __restrict__ bhn, float* __restrict__ out)
{
    const int lane = threadIdx.x & 63;
    const int wave = threadIdx.x >> 6;      // 0:agg 1:r 2:z 3:n
    const int row0 = blockIdx.x * 2;

    const float* Msel = (wave == 0) ? adj : (wave == 1) ? Whr
                      : (wave == 2) ? Whz : Whn;
    const float* Vsel = (wave == 0) ? x : h;
    const float4* M4 = reinterpret_cast<const float4*>(Msel) + (size_t)row0 * NV4;
    const float4* V4 = reinterpret_cast<const float4*>(Vsel);

    float acc0[BB], acc1[BB];
#pragma unroll
    for (int b = 0; b < BB; ++b) { acc0[b] = 0.f; acc1[b] = 0.f; }

    // 16 K-chunks; per iter: 2 matrix float4 + 8 vector float4 (L1-shared
    // across waves 1-3). No unroll pragma -- keep transient regs bounded.
    for (int it = 0; it < 16; ++it) {
        const int idx = it * 64 + lane;
        const float4 m0 = M4[idx];
        const float4 m1 = M4[idx + NV4];
        float4 v[BB];
#pragma unroll
        for (int b = 0; b < BB; ++b) v[b] = V4[b * NV4 + idx];
#pragma unroll
        for (int b = 0; b < BB; ++b) {
            acc0[b] += m0.x * v[b].x + m0.y * v[b].y + m0.z * v[b].z + m0.w * v[b].w;
            acc1[b] += m1.x * v[b].x + m1.y * v[b].y + m1.z * v[b].z + m1.w * v[b].w;
        }
    }

    // Full-wave butterfly: every lane ends with the gate's complete sums.
#pragma unroll
    for (int off = 32; off >= 1; off >>= 1) {
#pragma unroll
        for (int b = 0; b < BB; ++b) {
            acc0[b] += __shfl_xor(acc0[b], off);
            acc1[b] += __shfl_xor(acc1[b], off);
        }
    }

    __shared__ float red[4][2][BB];   // [gate][row][batch], 256 B
    if (lane == 0) {
#pragma unroll
        for (int b = 0; b < BB; ++b) {
            red[wave][0][b] = acc0[b];
            red[wave][1][b] = acc1[b];
        }
    }
    __syncthreads();

    const int t = threadIdx.x;
    if (t < 16) {
        const int r = t >> 3, b = t & 7;
        const int row = row0 + r;
        const float agg = red[0][r][b];
        const float rg = 1.f / (1.f + __expf(-(agg + red[1][r][b] + bhr[row])));
        const float zg = 1.f / (1.f + __expf(-(agg + red[2][r][b] + bhz[row])));
        const float ng = tanhf(agg + rg * (red[3][r][b] + bhn[row]));
        const float hv = h[b * NN + row];
        out[b * NN + row] = (1.f - zg) * ng + zg * hv;
    }
}

extern "C" void kernel_launch(void* const* d_in, const int* in_sizes, int n_in,
                              void* d_out, int out_size, void* d_ws, size_t ws_size,
                              hipStream_t stream) {
    const float* x   = (const float*)d_in[0];
    const float* h   = (const float*)d_in[1];
    const float* adj = (const float*)d_in[2];
    const float* Whr = (const float*)d_in[3];
    const float* bhr = (const float*)d_in[4];
    const float* Whz = (const float*)d_in[5];
    const float* bhz = (const float*)d_in[6];
    const float* Whn = (const float*)d_in[7];
    const float* bhn = (const float*)d_in[8];
    float* out = (float*)d_out;

    const int grid = NN / 2;   // 2048 blocks x 4 waves
    attgru_fused_kernel<<<grid, 256, 0, stream>>>(x, h, adj, Whr, bhr, Whz, bhz,
                                                  Whn, bhn, out);
}

// Round 4
// 79.487 us; speedup vs baseline: 5.6285x; 2.9436x over previous
//
#include <hip/hip_runtime.h>
#include <math.h>

#define NN 4096
#define BB 8
#define NV4 (NN / 4)     // float4 per row = 1024
#define KHALF (NV4 / 2)  // 512 float4 per K-half

// Block = 512 threads = 8 waves = 4 gates x 2 K-halves, for 2 output rows.
// Wave (g,kh) computes gate g's partial dot over K-half kh for both rows.
// Spill discipline (R1/R2 post-mortem): NO occupancy floor in launch_bounds
// -- (512,2) caps at 256 VGPR so the ~85 live regs never spill.
__global__ __launch_bounds__(512, 2) void attgru_fused_kernel(
    const float* __restrict__ x,   const float* __restrict__ h,
    const float* __restrict__ adj, const float* __restrict__ Whr,
    const float* __restrict__ bhr, const float* __restrict__ Whz,
    const float* __restrict__ bhz, const float* __restrict__ Whn,
    const float* __restrict__ bhn, float* __restrict__ out)
{
    const int lane  = threadIdx.x & 63;
    const int wave  = threadIdx.x >> 6;   // 0..7
    const int gate  = wave & 3;           // 0:agg 1:r 2:z 3:n
    const int khalf = wave >> 2;          // 0,1
    const int row0  = blockIdx.x * 2;

    const float* Msel = (gate == 0) ? adj : (gate == 1) ? Whr
                      : (gate == 2) ? Whz : Whn;
    const float* Vsel = (gate == 0) ? x : h;
    const float4* M4 = reinterpret_cast<const float4*>(Msel)
                     + (size_t)row0 * NV4 + khalf * KHALF;
    const float4* V4 = reinterpret_cast<const float4*>(Vsel) + khalf * KHALF;

    float acc0[BB], acc1[BB];
#pragma unroll
    for (int b = 0; b < BB; ++b) { acc0[b] = 0.f; acc1[b] = 0.f; }

    // 8 chunks of 64 float4 per wave; per iter: 2 matrix + 8 vector float4.
    for (int it = 0; it < 8; ++it) {
        const int idx = it * 64 + lane;
        const float4 m0 = M4[idx];
        const float4 m1 = M4[idx + NV4];
        float4 v[BB];
#pragma unroll
        for (int b = 0; b < BB; ++b) v[b] = V4[b * NV4 + idx];
#pragma unroll
        for (int b = 0; b < BB; ++b) {
            acc0[b] += m0.x * v[b].x + m0.y * v[b].y + m0.z * v[b].z + m0.w * v[b].w;
            acc1[b] += m1.x * v[b].x + m1.y * v[b].y + m1.z * v[b].z + m1.w * v[b].w;
        }
    }

    // Full-wave butterfly: lane 0 holds the wave's complete partials.
#pragma unroll
    for (int off = 32; off >= 1; off >>= 1) {
#pragma unroll
        for (int b = 0; b < BB; ++b) {
            acc0[b] += __shfl_xor(acc0[b], off);
            acc1[b] += __shfl_xor(acc1[b], off);
        }
    }

    __shared__ float red[8][2][BB];   // [wave][row][batch], 512 B
    if (lane == 0) {
#pragma unroll
        for (int b = 0; b < BB; ++b) {
            red[wave][0][b] = acc0[b];
            red[wave][1][b] = acc1[b];
        }
    }
    __syncthreads();

    const int t = threadIdx.x;
    if (t < 16) {
        const int r = t >> 3, b = t & 7;
        const int row = row0 + r;
        const float agg = red[0][r][b] + red[4][r][b];
        const float rs  = red[1][r][b] + red[5][r][b];
        const float zs  = red[2][r][b] + red[6][r][b];
        const float ns  = red[3][r][b] + red[7][r][b];
        const float rg = 1.f / (1.f + __expf(-(agg + rs + bhr[row])));
        const float zg = 1.f / (1.f + __expf(-(agg + zs + bhz[row])));
        const float ng = tanhf(agg + rg * (ns + bhn[row]));
        const float hv = h[b * NN + row];
        out[b * NN + row] = (1.f - zg) * ng + zg * hv;
    }
}

extern "C" void kernel_launch(void* const* d_in, const int* in_sizes, int n_in,
                              void* d_out, int out_size, void* d_ws, size_t ws_size,
                              hipStream_t stream) {
    const float* x   = (const float*)d_in[0];
    const float* h   = (const float*)d_in[1];
    const float* adj = (const float*)d_in[2];
    const float* Whr = (const float*)d_in[3];
    const float* bhr = (const float*)d_in[4];
    const float* Whz = (const float*)d_in[5];
    const float* bhz = (const float*)d_in[6];
    const float* Whn = (const float*)d_in[7];
    const float* bhn = (const float*)d_in[8];
    float* out = (float*)d_out;

    const int grid = NN / 2;   // 2048 blocks x 8 waves
    attgru_fused_kernel<<<grid, 512, 0, stream>>>(x, h, adj, Whr, bhr, Whz, bhz,
                                                  Whn, bhn, out);
}

// Round 5
// 63.202 us; speedup vs baseline: 7.0787x; 1.2577x over previous
//
#include <hip/hip_runtime.h>
#include <math.h>

#define NN 4096
#define BB 8
#define NV4 (NN / 4)   // float4 per row = 1024

// Block = 4 waves = 4 gates (adj·x, h·Whr, h·Whz, h·Whn), 2 rows/block.
// Per-thread live state kept < 64 VGPR (16 accs + 8 matrix + 16 vector regs)
// so the LB(256,4) occupancy floor cannot induce spills (R1/R2 post-mortem:
// compiler squeezes to exactly 64 VGPR; ~70 live regs then spill to scratch).
__global__ __launch_bounds__(256, 4) void attgru_fused_kernel(
    const float* __restrict__ x,   const float* __restrict__ h,
    const float* __restrict__ adj, const float* __restrict__ Whr,
    const float* __restrict__ bhr, const float* __restrict__ Whz,
    const float* __restrict__ bhz, const float* __restrict__ Whn,
    const float* __restrict__ bhn, float* __restrict__ out)
{
    const int lane = threadIdx.x & 63;
    const int wave = threadIdx.x >> 6;      // 0:agg 1:r 2:z 3:n
    const int row0 = blockIdx.x * 2;

    const float* Msel = (wave == 0) ? adj : (wave == 1) ? Whr
                      : (wave == 2) ? Whz : Whn;
    const float* Vsel = (wave == 0) ? x : h;
    const float4* M4 = reinterpret_cast<const float4*>(Msel) + (size_t)row0 * NV4;
    const float4* V4 = reinterpret_cast<const float4*>(Vsel);

    float acc0[BB], acc1[BB];
#pragma unroll
    for (int b = 0; b < BB; ++b) { acc0[b] = 0.f; acc1[b] = 0.f; }

    for (int it = 0; it < 16; ++it) {
        const int idx = it * 64 + lane;
        const float4 m0 = M4[idx];
        const float4 m1 = M4[idx + NV4];
        // Batches in two halves of 4: only 4 vector float4 live at a time.
        {
            float4 v0 = V4[0 * NV4 + idx], v1 = V4[1 * NV4 + idx];
            float4 v2 = V4[2 * NV4 + idx], v3 = V4[3 * NV4 + idx];
            acc0[0] += m0.x*v0.x + m0.y*v0.y + m0.z*v0.z + m0.w*v0.w;
            acc1[0] += m1.x*v0.x + m1.y*v0.y + m1.z*v0.z + m1.w*v0.w;
            acc0[1] += m0.x*v1.x + m0.y*v1.y + m0.z*v1.z + m0.w*v1.w;
            acc1[1] += m1.x*v1.x + m1.y*v1.y + m1.z*v1.z + m1.w*v1.w;
            acc0[2] += m0.x*v2.x + m0.y*v2.y + m0.z*v2.z + m0.w*v2.w;
            acc1[2] += m1.x*v2.x + m1.y*v2.y + m1.z*v2.z + m1.w*v2.w;
            acc0[3] += m0.x*v3.x + m0.y*v3.y + m0.z*v3.z + m0.w*v3.w;
            acc1[3] += m1.x*v3.x + m1.y*v3.y + m1.z*v3.z + m1.w*v3.w;
        }
        {
            float4 v4 = V4[4 * NV4 + idx], v5 = V4[5 * NV4 + idx];
            float4 v6 = V4[6 * NV4 + idx], v7 = V4[7 * NV4 + idx];
            acc0[4] += m0.x*v4.x + m0.y*v4.y + m0.z*v4.z + m0.w*v4.w;
            acc1[4] += m1.x*v4.x + m1.y*v4.y + m1.z*v4.z + m1.w*v4.w;
            acc0[5] += m0.x*v5.x + m0.y*v5.y + m0.z*v5.z + m0.w*v5.w;
            acc1[5] += m1.x*v5.x + m1.y*v5.y + m1.z*v5.z + m1.w*v5.w;
            acc0[6] += m0.x*v6.x + m0.y*v6.y + m0.z*v6.z + m0.w*v6.w;
            acc1[6] += m1.x*v6.x + m1.y*v6.y + m1.z*v6.z + m1.w*v6.w;
            acc0[7] += m0.x*v7.x + m0.y*v7.y + m0.z*v7.z + m0.w*v7.w;
            acc1[7] += m1.x*v7.x + m1.y*v7.y + m1.z*v7.z + m1.w*v7.w;
        }
    }

    // Full-wave butterfly: lane 0 ends with the gate's complete sums.
#pragma unroll
    for (int off = 32; off >= 1; off >>= 1) {
#pragma unroll
        for (int b = 0; b < BB; ++b) {
            acc0[b] += __shfl_xor(acc0[b], off);
            acc1[b] += __shfl_xor(acc1[b], off);
        }
    }

    __shared__ float red[4][2][BB];   // [gate][row][batch], 256 B
    if (lane == 0) {
#pragma unroll
        for (int b = 0; b < BB; ++b) {
            red[wave][0][b] = acc0[b];
            red[wave][1][b] = acc1[b];
        }
    }
    __syncthreads();

    const int t = threadIdx.x;
    if (t < 16) {
        const int r = t >> 3, b = t & 7;
        const int row = row0 + r;
        const float agg = red[0][r][b];
        const float rg = 1.f / (1.f + __expf(-(agg + red[1][r][b] + bhr[row])));
        const float zg = 1.f / (1.f + __expf(-(agg + red[2][r][b] + bhz[row])));
        const float ng = tanhf(agg + rg * (red[3][r][b] + bhn[row]));
        const float hv = h[b * NN + row];
        out[b * NN + row] = (1.f - zg) * ng + zg * hv;
    }
}

extern "C" void kernel_launch(void* const* d_in, const int* in_sizes, int n_in,
                              void* d_out, int out_size, void* d_ws, size_t ws_size,
                              hipStream_t stream) {
    const float* x   = (const float*)d_in[0];
    const float* h   = (const float*)d_in[1];
    const float* adj = (const float*)d_in[2];
    const float* Whr = (const float*)d_in[3];
    const float* bhr = (const float*)d_in[4];
    const float* Whz = (const float*)d_in[5];
    const float* bhz = (const float*)d_in[6];
    const float* Whn = (const float*)d_in[7];
    const float* bhn = (const float*)d_in[8];
    float* out = (float*)d_out;

    const int grid = NN / 2;   // 2048 blocks x 4 waves
    attgru_fused_kernel<<<grid, 256, 0, stream>>>(x, h, adj, Whr, bhr, Whz, bhz,
                                                  Whn, bhn, out);
}

// Round 6
// 57.876 us; speedup vs baseline: 7.7301x; 1.0920x over previous
//
#include <hip/hip_runtime.h>
#include <math.h>

#define NN 4096
#define BB 8
#define NV4 (NN / 4)        // float4 per row = 1024
#define CF4 64              // float4 per K-chunk (256 floats)
#define NCHUNK (NV4 / CF4)  // 16
#define ROWS 8              // rows per block
#define RPW 4               // rows per wave (2 row-groups)

// Block = 512 thr = 8 waves = 4 gates x 2 row-groups, 8 rows/block.
// x/h K-chunks staged in LDS once per block (double-buffered) -> vector
// traffic amortized over 8 rows (R4 post-mortem: per-wave vector re-reads
// = 1.31 GB register-delivered, L1-throughput-bound at ~33 us).
// Matrix double-buffered in regs. Live regs ~100 < 128 cap of LB(512,2).
__global__ __launch_bounds__(512, 2) void attgru_fused_kernel(
    const float* __restrict__ x,   const float* __restrict__ h,
    const float* __restrict__ adj, const float* __restrict__ Whr,
    const float* __restrict__ bhr, const float* __restrict__ Whz,
    const float* __restrict__ bhz, const float* __restrict__ Whn,
    const float* __restrict__ bhn, float* __restrict__ out)
{
    const int t    = threadIdx.x;
    const int lane = t & 63;
    const int wave = t >> 6;      // 0..7
    const int gate = wave >> 1;   // 0:agg 1:r 2:z 3:n
    const int rg   = wave & 1;    // row-group
    const int row0 = blockIdx.x * ROWS;

    __shared__ float4 vbuf[2][2][BB][CF4];  // [buf][x/h][batch][lane] 32 KB
    __shared__ float  red[8][RPW * BB];     // per-wave complete sums, 1 KB

    const float* Msel = (gate == 0) ? adj : (gate == 1) ? Whr
                      : (gate == 2) ? Whz : Whn;
    const int vsel = (gate != 0);
    const float4* M4 = reinterpret_cast<const float4*>(Msel)
                     + (size_t)(row0 + rg * RPW) * NV4;
    const float4* x4 = reinterpret_cast<const float4*>(x);
    const float4* h4 = reinterpret_cast<const float4*>(h);

    // Stage mapping: thread t stages batch (t>>6), lane (t&63) of x AND h.
    const int sb = t >> 6, sl = t & 63;
    const float4* srcx = x4 + sb * NV4 + sl;
    const float4* srch = h4 + sb * NV4 + sl;

    // ---- prologue: stage chunk 0, load matrix chunk 0 ----
    float4 mc[RPW];
#pragma unroll
    for (int r = 0; r < RPW; ++r) mc[r] = M4[r * NV4 + lane];
    {
        const float4 rx = srcx[0];
        const float4 rh = srch[0];
        vbuf[0][0][sb][sl] = rx;
        vbuf[0][1][sb][sl] = rh;
    }
    __syncthreads();

    float acc[RPW][BB];
#pragma unroll
    for (int r = 0; r < RPW; ++r)
#pragma unroll
        for (int b = 0; b < BB; ++b) acc[r][b] = 0.f;

    for (int c = 0; c < NCHUNK; ++c) {
        const int cur = c & 1, nxt = cur ^ 1;
        float4 rxn, rhn, mn[RPW];
        const bool more = (c + 1 < NCHUNK);
        if (more) {                       // issue next-chunk loads early
            rxn = srcx[(c + 1) * CF4];
            rhn = srch[(c + 1) * CF4];
#pragma unroll
            for (int r = 0; r < RPW; ++r)
                mn[r] = M4[r * NV4 + (c + 1) * CF4 + lane];
        }
        // compute current chunk: 8 LDS reads, 128 FMAs per lane
#pragma unroll
        for (int b = 0; b < BB; ++b) {
            const float4 vb = vbuf[cur][vsel][b][lane];
#pragma unroll
            for (int r = 0; r < RPW; ++r)
                acc[r][b] += mc[r].x * vb.x + mc[r].y * vb.y
                           + mc[r].z * vb.z + mc[r].w * vb.w;
        }
        if (more) {                       // write next buffer, rotate m regs
            vbuf[nxt][0][sb][sl] = rxn;
            vbuf[nxt][1][sb][sl] = rhn;
#pragma unroll
            for (int r = 0; r < RPW; ++r) mc[r] = mn[r];
        }
        __syncthreads();
    }

    // full-wave butterfly: all lanes end with the wave's complete sums
#pragma unroll
    for (int off = 32; off >= 1; off >>= 1)
#pragma unroll
        for (int r = 0; r < RPW; ++r)
#pragma unroll
            for (int b = 0; b < BB; ++b)
                acc[r][b] += __shfl_xor(acc[r][b], off);

    if (lane == 0) {
#pragma unroll
        for (int r = 0; r < RPW; ++r)
#pragma unroll
            for (int b = 0; b < BB; ++b)
                red[wave][r * BB + b] = acc[r][b];
    }
    __syncthreads();

    if (t < ROWS * BB) {   // 64 outputs per block
        const int r = t >> 3, b = t & 7;
        const int rgg = r >> 2, idx = (r & 3) * BB + b;
        const int row = row0 + r;
        const float agg = red[0 * 2 + rgg][idx];
        const float rs  = red[1 * 2 + rgg][idx];
        const float zs  = red[2 * 2 + rgg][idx];
        const float ns  = red[3 * 2 + rgg][idx];
        const float rgt = 1.f / (1.f + __expf(-(agg + rs + bhr[row])));
        const float zgt = 1.f / (1.f + __expf(-(agg + zs + bhz[row])));
        const float ngt = tanhf(agg + rgt * (ns + bhn[row]));
        const float hv  = h[b * NN + row];
        out[b * NN + row] = (1.f - zgt) * ngt + zgt * hv;
    }
}

extern "C" void kernel_launch(void* const* d_in, const int* in_sizes, int n_in,
                              void* d_out, int out_size, void* d_ws, size_t ws_size,
                              hipStream_t stream) {
    const float* x   = (const float*)d_in[0];
    const float* h   = (const float*)d_in[1];
    const float* adj = (const float*)d_in[2];
    const float* Whr = (const float*)d_in[3];
    const float* bhr = (const float*)d_in[4];
    const float* Whz = (const float*)d_in[5];
    const float* bhz = (const float*)d_in[6];
    const float* Whn = (const float*)d_in[7];
    const float* bhn = (const float*)d_in[8];
    float* out = (float*)d_out;

    const int grid = NN / ROWS;   // 512 blocks x 8 waves
    attgru_fused_kernel<<<grid, 512, 0, stream>>>(x, h, adj, Whr, bhr, Whz, bhz,
                                                  Whn, bhn, out);
}

// Round 7
// 55.935 us; speedup vs baseline: 7.9983x; 1.0347x over previous
//
#include <hip/hip_runtime.h>
#include <math.h>

#define NN 4096
#define BB 8
#define NV4 (NN / 4)        // float4 per row = 1024
#define CF4 128             // float4 per K-chunk (512 floats), 2 sub-passes
#define NCHUNK (NV4 / CF4)  // 8 -> 8 barriers instead of 16
#define ROWS 8              // rows per block
#define RPW 4               // rows per wave

// Block = 512 thr = 8 waves = 4 gates x 2 row-groups, 8 rows/block.
// R5 post-mortem: all pipe floors (VALU 7us, LDS 10us, HBM 21-42us) are
// below the measured 58us -> barrier/latency residue. This round: chunk =
// 512 floats split into two 64-lane sub-passes per barrier (8 barriers,
// ~2000cyc load slack vs ~900cyc HBM latency). Matrix regs rotate per
// sub-pass so peak live stays ~100 < LB(512,2)'s 128-VGPR cap (no spill).
__global__ __launch_bounds__(512, 2) void attgru_fused_kernel(
    const float* __restrict__ x,   const float* __restrict__ h,
    const float* __restrict__ adj, const float* __restrict__ Whr,
    const float* __restrict__ bhr, const float* __restrict__ Whz,
    const float* __restrict__ bhz, const float* __restrict__ Whn,
    const float* __restrict__ bhn, float* __restrict__ out)
{
    const int t    = threadIdx.x;
    const int lane = t & 63;
    const int wave = t >> 6;      // 0..7
    const int gate = wave >> 1;   // 0:agg 1:r 2:z 3:n
    const int rg   = wave & 1;    // row-group
    const int row0 = blockIdx.x * ROWS;

    __shared__ float4 vbuf[2][2][BB][CF4];  // [buf][x/h][batch][pos] 64 KB
    __shared__ float  red[8][RPW * BB];     // per-wave complete sums, 1 KB

    const float* Msel = (gate == 0) ? adj : (gate == 1) ? Whr
                      : (gate == 2) ? Whz : Whn;
    const int vsel = (gate != 0);
    const float4* M4 = reinterpret_cast<const float4*>(Msel)
                     + (size_t)(row0 + rg * RPW) * NV4;
    const float4* x4 = reinterpret_cast<const float4*>(x);
    const float4* h4 = reinterpret_cast<const float4*>(h);

    // Stage mapping: thread t stages batch (t>>6), positions sl and sl+64.
    const int sb = t >> 6, sl = t & 63;
    const float4* srcx = x4 + sb * NV4;
    const float4* srch = h4 + sb * NV4;

    // ---- prologue: stage chunk 0, load matrix sub0 of chunk 0 ----
    float4 mc[RPW];
#pragma unroll
    for (int r = 0; r < RPW; ++r) mc[r] = M4[r * NV4 + lane];
    {
        const float4 a0 = srcx[sl],      a1 = srcx[sl + 64];
        const float4 b0 = srch[sl],      b1 = srch[sl + 64];
        vbuf[0][0][sb][sl]      = a0;
        vbuf[0][0][sb][sl + 64] = a1;
        vbuf[0][1][sb][sl]      = b0;
        vbuf[0][1][sb][sl + 64] = b1;
    }
    __syncthreads();

    float acc[RPW][BB];
#pragma unroll
    for (int r = 0; r < RPW; ++r)
#pragma unroll
        for (int b = 0; b < BB; ++b) acc[r][b] = 0.f;

    for (int c = 0; c < NCHUNK; ++c) {
        const int cur = c & 1, nxt = cur ^ 1;
        const bool more = (c + 1 < NCHUNK);

        // issue next-chunk vector loads (longest path: HBM->reg->LDS->sync)
        float4 rx0, rx1, rh0, rh1;
        if (more) {
            const int vc = (c + 1) * CF4;
            rx0 = srcx[vc + sl];  rx1 = srcx[vc + sl + 64];
            rh0 = srch[vc + sl];  rh1 = srch[vc + sl + 64];
        }
        // matrix regs for sub1 of this chunk
        float4 mn[RPW];
#pragma unroll
        for (int r = 0; r < RPW; ++r)
            mn[r] = M4[r * NV4 + c * CF4 + 64 + lane];

        // ---- sub-pass 0: positions [0,64) ----
#pragma unroll
        for (int b = 0; b < BB; ++b) {
            const float4 vb = vbuf[cur][vsel][b][lane];
#pragma unroll
            for (int r = 0; r < RPW; ++r)
                acc[r][b] += mc[r].x * vb.x + mc[r].y * vb.y
                           + mc[r].z * vb.z + mc[r].w * vb.w;
        }

        // prefetch matrix sub0 of next chunk (after sub0 compute: transients
        // never stack past ~100 live regs)
        float4 mc2[RPW];
        if (more) {
#pragma unroll
            for (int r = 0; r < RPW; ++r)
                mc2[r] = M4[r * NV4 + (c + 1) * CF4 + lane];
        }

        // ---- sub-pass 1: positions [64,128) ----
#pragma unroll
        for (int b = 0; b < BB; ++b) {
            const float4 vb = vbuf[cur][vsel][b][64 + lane];
#pragma unroll
            for (int r = 0; r < RPW; ++r)
                acc[r][b] += mn[r].x * vb.x + mn[r].y * vb.y
                           + mn[r].z * vb.z + mn[r].w * vb.w;
        }

        if (more) {
            vbuf[nxt][0][sb][sl]      = rx0;
            vbuf[nxt][0][sb][sl + 64] = rx1;
            vbuf[nxt][1][sb][sl]      = rh0;
            vbuf[nxt][1][sb][sl + 64] = rh1;
#pragma unroll
            for (int r = 0; r < RPW; ++r) mc[r] = mc2[r];
            __syncthreads();
        }
    }

    // full-wave butterfly: all lanes end with the wave's complete sums
#pragma unroll
    for (int off = 32; off >= 1; off >>= 1)
#pragma unroll
        for (int r = 0; r < RPW; ++r)
#pragma unroll
            for (int b = 0; b < BB; ++b)
                acc[r][b] += __shfl_xor(acc[r][b], off);

    if (lane == 0) {
#pragma unroll
        for (int r = 0; r < RPW; ++r)
#pragma unroll
            for (int b = 0; b < BB; ++b)
                red[wave][r * BB + b] = acc[r][b];
    }
    __syncthreads();

    if (t < ROWS * BB) {   // 64 outputs per block
        const int r = t >> 3, b = t & 7;
        const int rgg = r >> 2, idx = (r & 3) * BB + b;
        const int row = row0 + r;
        const float agg = red[0 * 2 + rgg][idx];
        const float rs  = red[1 * 2 + rgg][idx];
        const float zs  = red[2 * 2 + rgg][idx];
        const float ns  = red[3 * 2 + rgg][idx];
        const float rgt = 1.f / (1.f + __expf(-(agg + rs + bhr[row])));
        const float zgt = 1.f / (1.f + __expf(-(agg + zs + bhz[row])));
        const float ngt = tanhf(agg + rgt * (ns + bhn[row]));
        const float hv  = h[b * NN + row];
        out[b * NN + row] = (1.f - zgt) * ngt + zgt * hv;
    }
}

extern "C" void kernel_launch(void* const* d_in, const int* in_sizes, int n_in,
                              void* d_out, int out_size, void* d_ws, size_t ws_size,
                              hipStream_t stream) {
    const float* x   = (const float*)d_in[0];
    const float* h   = (const float*)d_in[1];
    const float* adj = (const float*)d_in[2];
    const float* Whr = (const float*)d_in[3];
    const float* bhr = (const float*)d_in[4];
    const float* Whz = (const float*)d_in[5];
    const float* bhz = (const float*)d_in[6];
    const float* Whn = (const float*)d_in[7];
    const float* bhn = (const float*)d_in[8];
    float* out = (float*)d_out;

    const int grid = NN / ROWS;   // 512 blocks x 8 waves
    attgru_fused_kernel<<<grid, 512, 0, stream>>>(x, h, adj, Whr, bhr, Whz, bhz,
                                                  Whn, bhn, out);
}